// Round 1
// baseline (1041.494 us; speedup 1.0000x reference)
//
#include <hip/hip_runtime.h>
#include <math.h>

// Problem constants (fixed by the reference module)
#define TPB 256
constexpr int Mm   = 16;
constexpr int Kk   = 512;
constexpr int Pp   = 2048;
constexpr int Ll   = 1024;
constexpr int Nn   = Mm * Kk;            // 8192 rows
constexpr int SO   = 40;                  // simulator_offset
constexpr int DMAX = 320;                 // delay_max * fs
constexpr int Dd   = DMAX + 2 * SO;       // 400
constexpr int XLEN = Pp + Ll - 1;         // 3071
constexpr size_t XTOT = (size_t)Nn * XLEN;
constexpr int HPAD  = 400;                // pad for conv1 offsets (|off| <= 399)
constexpr int HPLEN = HPAD + Pp + HPAD;   // 2848
constexpr int HCLEN = 4096;               // 1024 zero | 2048 H_est | 1024 zero

__global__ __launch_bounds__(TPB, 4)
void fused_row_kernel(const float* __restrict__ U,
                      const float* __restrict__ Hn,
                      const float* __restrict__ v,
                      const float* __restrict__ mtoa,
                      float* __restrict__ out)
{
    __shared__ float swin[Dd];
    __shared__ float stap[81];
    __shared__ float sHp[HPLEN];
    __shared__ float shc[HCLEN];
    __shared__ float svs[Ll];
    __shared__ float sval[TPB];
    __shared__ int   sidx[TPB];

    const int n   = blockIdx.x;
    const int tid = threadIdx.x;
    const int m_i = n >> 9;    // n / 512
    const int k_i = n & 511;   // n % 512

    // ---- stage v (1024 floats) and H row (2048 floats) into LDS ----
    *(float4*)&svs[tid * 4] = ((const float4*)v)[tid];
    {
        const float4* h4 = (const float4*)(Hn + (size_t)n * Pp);
        *(float4*)&sHp[HPAD + tid * 8]     = h4[tid * 2];
        *(float4*)&sHp[HPAD + tid * 8 + 4] = h4[tid * 2 + 1];
    }
    // zero pads of sHp (400 floats each side)
    for (int j = tid; j < HPAD; j += TPB) {
        sHp[j] = 0.0f;
        sHp[HPAD + Pp + j] = 0.0f;
    }
    // zero pads of shc (1024 floats each side)
    for (int j = tid; j < 1024; j += TPB) {
        shc[j] = 0.0f;
        shc[1024 + Pp + j] = 0.0f;
    }

    // ---- per-row scalars (computed redundantly per thread; trivial) ----
    const float u  = U[n];
    const float mt = mtoa[n];
    float th = tanhf(u);
    if (isnan(th)) th = 0.0f;               // nan_to_num
    const float delta = 0.02f * th;          // delay_max * tanh
    const float frac  = delta * 16000.0f;    // * fs
    const float af    = fabsf(frac);
    float nt = delta + mt;
    if (nt == 0.0f) nt = 1.0f;
    const float ratio = mt / nt;
    const bool  isneg = frac < 0.0f;

    // ---- win[t] = ratio * 0.5 * (1 + cos(2*pi*T/80)) * sinc(T) ----
    for (int t = tid; t < Dd; t += TPB) {
        float T  = (float)(t - SO) - af;
        float c  = cosf((6.28318530717958648f * T) / 80.0f);
        float px = 3.14159265358979324f * T;
        float sc = (T == 0.0f) ? 1.0f : (sinf(px) / px);
        float w  = ratio * 0.5f;   // match reference eval order
        w = w * (1.0f + c);
        w = w * sc;
        swin[t] = w;
    }
    __syncthreads();

    // ---- block argmax with first-index tie-break (match jnp.argmax) ----
    float lv = swin[tid];
    int   li = tid;
    {
        int t2 = tid + TPB;
        if (t2 < Dd) {
            float v2 = swin[t2];
            if (v2 > lv) { lv = v2; li = t2; }
        }
    }
    sval[tid] = lv; sidx[tid] = li;
    __syncthreads();
    for (int s = TPB / 2; s > 0; s >>= 1) {
        if (tid < s) {
            float av = sval[tid];     int ai = sidx[tid];
            float bv = sval[tid + s]; int bi = sidx[tid + s];
            if (bv > av || (bv == av && bi < ai)) { sval[tid] = bv; sidx[tid] = bi; }
        }
        __syncthreads();
    }
    const int am = sidx[0];

    // ---- extract the <=81 surviving taps ----
    if (tid < 81) {
        int w = am - 40 + tid;
        stap[tid] = (w >= 0 && w < Dd) ? swin[w] : 0.0f;
    }
    __syncthreads();

    // ---- conv1: H_est[i] = sum_p stap[p] * H[i + sgn*(80 - am - p)] ----
    const int sgn = isneg ? -1 : 1;
    float* hout = out + XTOT + (size_t)n * Pp;
    for (int j = 0; j < Pp / TPB; ++j) {
        int i = tid + j * TPB;
        int base = HPAD + i + sgn * (80 - am);
        float acc = 0.0f;
        #pragma unroll
        for (int p = 0; p < 81; ++p)
            acc += stap[p] * sHp[base - sgn * p];
        hout[i] = acc;           // H_est output (second tuple element)
        shc[1024 + i] = acc;     // staged for conv2
    }
    __syncthreads();

    // ---- conv2: x[t] = sum_k v[k] * H_est[t-k], register-blocked 12 outs/thread ----
    const int t0 = tid * 12;     // 256*12 = 3072 >= 3071
    float acc[12];
    #pragma unroll
    for (int i = 0; i < 12; ++i) acc[i] = 0.0f;

    int kend = t0 + 11;            if (kend > Ll - 1) kend = Ll - 1;
    int kstart = t0 - (Pp - 1);    if (kstart < 0)     kstart = 0;
    kstart &= ~3;                  // align down; extra taps hit zero padding

    for (int k0 = kstart; k0 <= kend; k0 += 4) {
        float4 vv = *(const float4*)&svs[k0];
        int A = 1024 + t0 - k0 - 4;                    // multiple of 4 -> aligned b128 reads
        float4 w0 = *(const float4*)&shc[A];
        float4 w1 = *(const float4*)&shc[A + 4];
        float4 w2 = *(const float4*)&shc[A + 8];
        float4 w3 = *(const float4*)&shc[A + 12];
        float W[16] = { w0.x, w0.y, w0.z, w0.w,
                        w1.x, w1.y, w1.z, w1.w,
                        w2.x, w2.y, w2.z, w2.w,
                        w3.x, w3.y, w3.z, w3.w };
        float vk[4] = { vv.x, vv.y, vv.z, vv.w };
        #pragma unroll
        for (int kk = 0; kk < 4; ++kk) {
            #pragma unroll
            for (int i = 0; i < 12; ++i)
                acc[i] += vk[kk] * W[i - kk + 4];      // index in [1,15], compile-time const
        }
    }

    // x output layout: (K, M, XLEN) after transpose(1,0,2)
    float* xrow = out + (size_t)(k_i * Mm + m_i) * XLEN;
    #pragma unroll
    for (int i = 0; i < 12; ++i) {
        int t = t0 + i;
        if (t < XLEN) xrow[t] = acc[i];
    }
}

extern "C" void kernel_launch(void* const* d_in, const int* in_sizes, int n_in,
                              void* d_out, int out_size, void* d_ws, size_t ws_size,
                              hipStream_t stream) {
    const float* U    = (const float*)d_in[0];
    const float* Hn   = (const float*)d_in[1];
    const float* v    = (const float*)d_in[2];
    const float* mtoa = (const float*)d_in[3];
    float* out = (float*)d_out;

    fused_row_kernel<<<Nn, TPB, 0, stream>>>(U, Hn, v, mtoa, out);
}

// Round 2
// 636.542 us; speedup vs baseline: 1.6362x; 1.6362x over previous
//
#include <hip/hip_runtime.h>
#include <math.h>
#include <stdint.h>

#define TPB 256
constexpr int Mm   = 16;
constexpr int Kk   = 512;
constexpr int Pp   = 2048;
constexpr int Ll   = 1024;
constexpr int Nn   = Mm * Kk;            // 8192 rows
constexpr int SO   = 40;
constexpr int DMAX = 320;
constexpr int Dd   = DMAX + 2 * SO;       // 400
constexpr int XLEN = Pp + Ll - 1;         // 3071
constexpr size_t XTOT = (size_t)Nn * XLEN;
constexpr int HPAD  = 400;
constexpr int HPLEN = HPAD + Pp + HPAD;   // 2848
constexpr int HCLEN = 4096;

typedef __attribute__((ext_vector_type(8))) short  short8;
typedef __attribute__((ext_vector_type(4))) float  f32x4;

__device__ __forceinline__ uint32_t bf16rn(float x) {
    uint32_t u = __float_as_uint(x);
    return (u + 0x7fffu + ((u >> 16) & 1u)) >> 16;   // round-to-nearest-even bf16
}

__device__ __forceinline__ void gload16(const void* g, void* l) {
    __builtin_amdgcn_global_load_lds(
        (const __attribute__((address_space(1))) uint32_t*)g,
        (__attribute__((address_space(3))) uint32_t*)l,
        16, 0, 0);
}

// ===================== Kernel 1: window + argmax + conv1 =====================
__global__ __launch_bounds__(TPB)
void winconv_kernel(const float* __restrict__ U,
                    const float* __restrict__ Hn,
                    const float* __restrict__ mtoa,
                    float* __restrict__ out,
                    ushort* __restrict__ whi,
                    ushort* __restrict__ wlo)
{
    __shared__ float swin[Dd];
    __shared__ float stap[81];
    __shared__ float sHp[HPLEN];
    __shared__ float sval[TPB];
    __shared__ int   sidx[TPB];

    const int n   = blockIdx.x;
    const int tid = threadIdx.x;

    {
        const float4* h4 = (const float4*)(Hn + (size_t)n * Pp);
        *(float4*)&sHp[HPAD + tid * 8]     = h4[tid * 2];
        *(float4*)&sHp[HPAD + tid * 8 + 4] = h4[tid * 2 + 1];
    }
    for (int j = tid; j < HPAD; j += TPB) {
        sHp[j] = 0.0f;
        sHp[HPAD + Pp + j] = 0.0f;
    }

    const float u  = U[n];
    const float mt = mtoa[n];
    float th = tanhf(u);
    if (isnan(th)) th = 0.0f;
    const float delta = 0.02f * th;
    const float frac  = delta * 16000.0f;
    const float af    = fabsf(frac);
    float nt = delta + mt;
    if (nt == 0.0f) nt = 1.0f;
    const float ratio = mt / nt;
    const bool  isneg = frac < 0.0f;

    for (int t = tid; t < Dd; t += TPB) {
        float T  = (float)(t - SO) - af;
        float c  = cosf((6.28318530717958648f * T) / 80.0f);
        float px = 3.14159265358979324f * T;
        float sc = (T == 0.0f) ? 1.0f : (sinf(px) / px);
        float w  = ratio * 0.5f;
        w = w * (1.0f + c);
        w = w * sc;
        swin[t] = w;
    }
    __syncthreads();

    float lv = swin[tid];
    int   li = tid;
    {
        int t2 = tid + TPB;
        if (t2 < Dd) {
            float v2 = swin[t2];
            if (v2 > lv) { lv = v2; li = t2; }
        }
    }
    sval[tid] = lv; sidx[tid] = li;
    __syncthreads();
    for (int s = TPB / 2; s > 0; s >>= 1) {
        if (tid < s) {
            float av = sval[tid];     int ai = sidx[tid];
            float bv = sval[tid + s]; int bi = sidx[tid + s];
            if (bv > av || (bv == av && bi < ai)) { sval[tid] = bv; sidx[tid] = bi; }
        }
        __syncthreads();
    }
    const int am = sidx[0];

    if (tid < 81) {
        int w = am - 40 + tid;
        stap[tid] = (w >= 0 && w < Dd) ? swin[w] : 0.0f;
    }
    __syncthreads();

    const int sgn = isneg ? -1 : 1;
    float*  hout = out + XTOT + (size_t)n * Pp;
    ushort* hih  = whi + (size_t)n * Pp;
    ushort* loh  = wlo + (size_t)n * Pp;
    for (int j = 0; j < Pp / TPB; ++j) {
        int i = tid + j * TPB;
        int base = HPAD + i + sgn * (80 - am);
        float acc = 0.0f;
        #pragma unroll
        for (int p = 0; p < 81; ++p)
            acc += stap[p] * sHp[base - sgn * p];
        hout[i] = acc;
        uint32_t rh = bf16rn(acc);
        float hf = __uint_as_float(rh << 16);
        uint32_t rl = bf16rn(acc - hf);
        hih[i] = (ushort)rh;
        loh[i] = (ushort)rl;
    }
}

// ===================== Kernel 2: banded Toeplitz GEMM (bf16 MFMA, 3-pass) ====
constexpr int BN2 = 128;
constexpr int BT2 = 64;
constexpr int BK2 = 32;
constexpr int NB2 = Nn / BN2;         // 64
constexpr int TB2 = 3072 / BT2;       // 48
constexpr int RSTR = 1176;

__global__ __launch_bounds__(TPB, 2)
void toep_gemm(const float* __restrict__ v,
               const ushort* __restrict__ whi,
               const ushort* __restrict__ wlo,
               float* __restrict__ out)
{
    __shared__ alignas(16) ushort sA[2][2][BN2 * BK2];   // 32 KB
    __shared__ alignas(16) ushort sRV[2][8 * RSTR];      // 37.6 KB

    const int tid  = threadIdx.x;
    const int lane = tid & 63;
    const int w    = tid >> 6;

    int bid = blockIdx.x;
    int wg  = (bid & 7) * (NB2 * TB2 / 8) + (bid >> 3);
    const int nb = wg / TB2;
    const int tb = wg - nb * TB2;
    const int n0 = nb * BN2;
    const int t0 = tb * BT2;

    for (int idx = tid; idx < 8 * RSTR; idx += TPB) {
        int r = idx / RSTR, m = idx - r * RSTR;
        int q = m + r - 64;
        float val = (q >= 0 && q < Ll) ? v[1023 - q] : 0.0f;
        uint32_t rh = bf16rn(val);
        float hf = __uint_as_float(rh << 16);
        uint32_t rl = bf16rn(val - hf);
        sRV[0][idx] = (ushort)rh;
        sRV[1][idx] = (ushort)rl;
    }

    const int s_begin = max(0, 32 - (t0 >> 5));
    const int s_end   = min(34, 96 - (t0 >> 5));
    const int jstart  = t0 - 1024;

    auto stage = [&](int buf, int s) {
        int j0 = jstart + (s << 5);
        #pragma unroll
        for (int hl = 0; hl < 2; ++hl) {
            const ushort* src = hl ? wlo : whi;
            #pragma unroll
            for (int i = 0; i < 2; ++i) {
                int slotb = w * 128 + i * 64;
                int slot  = slotb + lane;
                int row   = slot >> 2, pc = slot & 3;
                int gs    = pc ^ ((row >> 1) & 3);
                const ushort* g = src + (size_t)(n0 + row) * Pp + (j0 + gs * 8);
                gload16(g, (void*)&sA[buf][hl][slotb * 8]);
            }
        }
    };

    f32x4 acc[2][4];
    #pragma unroll
    for (int a = 0; a < 2; ++a)
        #pragma unroll
        for (int b = 0; b < 4; ++b)
            acc[a][b] = (f32x4){0.f, 0.f, 0.f, 0.f};

    int cur = 0;
    stage(0, s_begin);
    __syncthreads();

    for (int s = s_begin; s < s_end; ++s) {
        if (s + 1 < s_end) stage(cur ^ 1, s + 1);

        short8 ah[2], alo[2];
        #pragma unroll
        for (int fr = 0; fr < 2; ++fr) {
            int row = (w << 5) + (fr << 4) + (lane & 15);
            int g   = lane >> 4;
            int pc  = g ^ ((row >> 1) & 3);
            int off = row * 32 + pc * 8;
            ah[fr]  = *(const short8*)&sA[cur][0][off];
            alo[fr] = *(const short8*)&sA[cur][1][off];
        }

        int sBase = (s << 5) + 63 + ((lane >> 4) << 3) - (lane & 15);
        #pragma unroll
        for (int cc = 0; cc < 4; ++cc) {
            int b   = sBase - (cc << 4);
            int rep = b & 7, alg = b & ~7;
            int off = rep * RSTR + alg;
            short8 bh = *(const short8*)&sRV[0][off];
            short8 bl = *(const short8*)&sRV[1][off];
            #pragma unroll
            for (int fr = 0; fr < 2; ++fr) {
                acc[fr][cc] = __builtin_amdgcn_mfma_f32_16x16x32_bf16(ah[fr],  bh, acc[fr][cc], 0, 0, 0);
                acc[fr][cc] = __builtin_amdgcn_mfma_f32_16x16x32_bf16(ah[fr],  bl, acc[fr][cc], 0, 0, 0);
                acc[fr][cc] = __builtin_amdgcn_mfma_f32_16x16x32_bf16(alo[fr], bh, acc[fr][cc], 0, 0, 0);
            }
        }
        __syncthreads();
        cur ^= 1;
    }

    #pragma unroll
    for (int fr = 0; fr < 2; ++fr) {
        #pragma unroll
        for (int cc = 0; cc < 4; ++cc) {
            int t = t0 + (cc << 4) + (lane & 15);
            if (t < XLEN) {
                int nbase = n0 + (w << 5) + (fr << 4) + ((lane >> 4) << 2);
                #pragma unroll
                for (int i = 0; i < 4; ++i) {
                    int nn = nbase + i;
                    int mi = nn >> 9, ki = nn & 511;
                    out[(size_t)(ki * Mm + mi) * XLEN + t] = acc[fr][cc][i];
                }
            }
        }
    }
}

// ===================== Legacy fallback (R1 monolith) =========================
__global__ __launch_bounds__(TPB, 4)
void fused_row_kernel(const float* __restrict__ U,
                      const float* __restrict__ Hn,
                      const float* __restrict__ v,
                      const float* __restrict__ mtoa,
                      float* __restrict__ out)
{
    __shared__ float swin[Dd];
    __shared__ float stap[81];
    __shared__ float sHp[HPLEN];
    __shared__ float shc[HCLEN];
    __shared__ float svs[Ll];
    __shared__ float sval[TPB];
    __shared__ int   sidx[TPB];

    const int n   = blockIdx.x;
    const int tid = threadIdx.x;
    const int m_i = n >> 9;
    const int k_i = n & 511;

    *(float4*)&svs[tid * 4] = ((const float4*)v)[tid];
    {
        const float4* h4 = (const float4*)(Hn + (size_t)n * Pp);
        *(float4*)&sHp[HPAD + tid * 8]     = h4[tid * 2];
        *(float4*)&sHp[HPAD + tid * 8 + 4] = h4[tid * 2 + 1];
    }
    for (int j = tid; j < HPAD; j += TPB) {
        sHp[j] = 0.0f;
        sHp[HPAD + Pp + j] = 0.0f;
    }
    for (int j = tid; j < 1024; j += TPB) {
        shc[j] = 0.0f;
        shc[1024 + Pp + j] = 0.0f;
    }

    const float u  = U[n];
    const float mt = mtoa[n];
    float th = tanhf(u);
    if (isnan(th)) th = 0.0f;
    const float delta = 0.02f * th;
    const float frac  = delta * 16000.0f;
    const float af    = fabsf(frac);
    float nt = delta + mt;
    if (nt == 0.0f) nt = 1.0f;
    const float ratio = mt / nt;
    const bool  isneg = frac < 0.0f;

    for (int t = tid; t < Dd; t += TPB) {
        float T  = (float)(t - SO) - af;
        float c  = cosf((6.28318530717958648f * T) / 80.0f);
        float px = 3.14159265358979324f * T;
        float sc = (T == 0.0f) ? 1.0f : (sinf(px) / px);
        float w  = ratio * 0.5f;
        w = w * (1.0f + c);
        w = w * sc;
        swin[t] = w;
    }
    __syncthreads();

    float lv = swin[tid];
    int   li = tid;
    {
        int t2 = tid + TPB;
        if (t2 < Dd) {
            float v2 = swin[t2];
            if (v2 > lv) { lv = v2; li = t2; }
        }
    }
    sval[tid] = lv; sidx[tid] = li;
    __syncthreads();
    for (int s = TPB / 2; s > 0; s >>= 1) {
        if (tid < s) {
            float av = sval[tid];     int ai = sidx[tid];
            float bv = sval[tid + s]; int bi = sidx[tid + s];
            if (bv > av || (bv == av && bi < ai)) { sval[tid] = bv; sidx[tid] = bi; }
        }
        __syncthreads();
    }
    const int am = sidx[0];

    if (tid < 81) {
        int w = am - 40 + tid;
        stap[tid] = (w >= 0 && w < Dd) ? swin[w] : 0.0f;
    }
    __syncthreads();

    const int sgn = isneg ? -1 : 1;
    float* hout = out + XTOT + (size_t)n * Pp;
    for (int j = 0; j < Pp / TPB; ++j) {
        int i = tid + j * TPB;
        int base = HPAD + i + sgn * (80 - am);
        float acc = 0.0f;
        #pragma unroll
        for (int p = 0; p < 81; ++p)
            acc += stap[p] * sHp[base - sgn * p];
        hout[i] = acc;
        shc[1024 + i] = acc;
    }
    __syncthreads();

    const int t0 = tid * 12;
    float acc[12];
    #pragma unroll
    for (int i = 0; i < 12; ++i) acc[i] = 0.0f;

    int kend = t0 + 11;            if (kend > Ll - 1) kend = Ll - 1;
    int kstart = t0 - (Pp - 1);    if (kstart < 0)     kstart = 0;
    kstart &= ~3;

    for (int k0 = kstart; k0 <= kend; k0 += 4) {
        float4 vv = *(const float4*)&svs[k0];
        int A = 1024 + t0 - k0 - 4;
        float4 w0 = *(const float4*)&shc[A];
        float4 w1 = *(const float4*)&shc[A + 4];
        float4 w2 = *(const float4*)&shc[A + 8];
        float4 w3 = *(const float4*)&shc[A + 12];
        float W[16] = { w0.x, w0.y, w0.z, w0.w,
                        w1.x, w1.y, w1.z, w1.w,
                        w2.x, w2.y, w2.z, w2.w,
                        w3.x, w3.y, w3.z, w3.w };
        float vk[4] = { vv.x, vv.y, vv.z, vv.w };
        #pragma unroll
        for (int kk = 0; kk < 4; ++kk) {
            #pragma unroll
            for (int i = 0; i < 12; ++i)
                acc[i] += vk[kk] * W[i - kk + 4];
        }
    }

    float* xrow = out + (size_t)(k_i * Mm + m_i) * XLEN;
    #pragma unroll
    for (int i = 0; i < 12; ++i) {
        int t = t0 + i;
        if (t < XLEN) xrow[t] = acc[i];
    }
}

extern "C" void kernel_launch(void* const* d_in, const int* in_sizes, int n_in,
                              void* d_out, int out_size, void* d_ws, size_t ws_size,
                              hipStream_t stream) {
    const float* U    = (const float*)d_in[0];
    const float* Hn   = (const float*)d_in[1];
    const float* v    = (const float*)d_in[2];
    const float* mtoa = (const float*)d_in[3];
    float* out = (float*)d_out;

    const size_t need = (size_t)Nn * Pp * sizeof(ushort) * 2;  // hi+lo = 67.1 MB
    if (ws_size >= need) {
        ushort* whi = (ushort*)d_ws;
        ushort* wlo = whi + (size_t)Nn * Pp;
        winconv_kernel<<<Nn, TPB, 0, stream>>>(U, Hn, mtoa, out, whi, wlo);
        toep_gemm<<<NB2 * TB2, TPB, 0, stream>>>(v, whi, wlo, out);
    } else {
        fused_row_kernel<<<Nn, TPB, 0, stream>>>(U, Hn, v, mtoa, out);
    }
}

// Round 5
// 445.259 us; speedup vs baseline: 2.3391x; 1.4296x over previous
//
#include <hip/hip_runtime.h>
#include <math.h>
#include <stdint.h>

#define TPB 256
constexpr int Mm   = 16;
constexpr int Kk   = 512;
constexpr int Pp   = 2048;
constexpr int Ll   = 1024;
constexpr int Nn   = Mm * Kk;            // 8192 rows
constexpr int SO   = 40;
constexpr int DMAX = 320;
constexpr int Dd   = DMAX + 2 * SO;       // 400
constexpr int XLEN = Pp + Ll - 1;         // 3071
constexpr size_t XTOT = (size_t)Nn * XLEN;
constexpr int HPAD  = 400;
constexpr int HPLEN = 2864;               // left pad 400 | 2048 data | right pad 416
constexpr int HCLEN = 4096;

typedef __attribute__((ext_vector_type(8))) short  short8;
typedef __attribute__((ext_vector_type(8))) ushort ushort8;
typedef __attribute__((ext_vector_type(4))) float  f32x4;

__device__ __forceinline__ uint32_t bf16rn(float x) {
    uint32_t u = __float_as_uint(x);
    return (u + 0x7fffu + ((u >> 16) & 1u)) >> 16;   // round-to-nearest-even bf16
}

__device__ __forceinline__ void gload16(const void* g, void* l) {
    __builtin_amdgcn_global_load_lds(
        (const __attribute__((address_space(1))) uint32_t*)g,
        (__attribute__((address_space(3))) uint32_t*)l,
        16, 0, 0);
}

// ===================== Kernel 1: window + argmax + conv1 =====================
__global__ __launch_bounds__(TPB)
void winconv_kernel(const float* __restrict__ U,
                    const float* __restrict__ Hn,
                    const float* __restrict__ mtoa,
                    float* __restrict__ out,
                    ushort* __restrict__ whi,
                    ushort* __restrict__ wlo)
{
    __shared__ float swin[Dd];
    __shared__ float staps[96];            // e zeros | 81 taps (direction-normalized) | zeros
    __shared__ float sHp[HPLEN];
    __shared__ float sval[TPB];
    __shared__ int   sidx[TPB];

    const int n   = blockIdx.x;
    const int tid = threadIdx.x;

    // stage H row (2048 floats) + zero pads
    {
        const float4* h4 = (const float4*)(Hn + (size_t)n * Pp);
        *(float4*)&sHp[HPAD + tid * 8]     = h4[tid * 2];
        *(float4*)&sHp[HPAD + tid * 8 + 4] = h4[tid * 2 + 1];
    }
    for (int j = tid; j < HPAD; j += TPB) sHp[j] = 0.0f;
    for (int j = tid; j < HPLEN - (HPAD + Pp); j += TPB) sHp[HPAD + Pp + j] = 0.0f;

    const float u  = U[n];
    const float mt = mtoa[n];
    float th = tanhf(u);
    if (isnan(th)) th = 0.0f;
    const float delta = 0.02f * th;
    const float frac  = delta * 16000.0f;
    const float af    = fabsf(frac);
    float nt = delta + mt;
    if (nt == 0.0f) nt = 1.0f;
    const float ratio = mt / nt;
    const bool  isneg = frac < 0.0f;

    for (int t = tid; t < Dd; t += TPB) {
        float T  = (float)(t - SO) - af;
        float c  = cosf((6.28318530717958648f * T) / 80.0f);
        float px = 3.14159265358979324f * T;
        float sc = (T == 0.0f) ? 1.0f : (sinf(px) / px);
        float w  = ratio * 0.5f;
        w = w * (1.0f + c);
        w = w * sc;
        swin[t] = w;
    }
    __syncthreads();

    // block argmax, first-index tie-break
    float lv = swin[tid];
    int   li = tid;
    {
        int t2 = tid + TPB;
        if (t2 < Dd) {
            float v2 = swin[t2];
            if (v2 > lv) { lv = v2; li = t2; }
        }
    }
    sval[tid] = lv; sidx[tid] = li;
    __syncthreads();
    for (int s = TPB / 2; s > 0; s >>= 1) {
        if (tid < s) {
            float av = sval[tid];     int ai = sidx[tid];
            float bv = sval[tid + s]; int bi = sidx[tid + s];
            if (bv > av || (bv == av && bi < ai)) { sval[tid] = bv; sidx[tid] = bi; }
        }
        __syncthreads();
    }
    const int am = sidx[0];

    // Direction-normalized taps:
    //   frac>=0: H_est[i] = sum_q stap[80-q] * sHp[(HPAD-am)      + i + q]
    //   frac<0 : H_est[i] = sum_q stap[q]    * sHp[(HPAD-80+am)   + i + q]
    // where stap[p] = swin[am-40+p] (0 outside). Pad with e = b0&3 leading zeros
    // so the sHp base is 4-aligned.
    const int b0 = isneg ? (HPAD - 80 + am) : (HPAD - am);
    const int e  = b0 & 3;
    const int A0 = b0 - e;                 // 4-aligned
    if (tid < 96) {
        float val = 0.0f;
        int q = tid - e;
        if (q >= 0 && q <= 80) {
            int p = isneg ? q : (80 - q);
            int w = am - 40 + p;
            val = (w >= 0 && w < Dd) ? swin[w] : 0.0f;
        }
        staps[tid] = val;
    }
    __syncthreads();

    // conv1: 8 consecutive outputs/thread, sliding 12-float register window
    const int i0 = tid * 8;
    const int A  = A0 + i0;
    float acc[8];
    #pragma unroll
    for (int k = 0; k < 8; ++k) acc[k] = 0.0f;

    float W[12];
    {
        float4 w0 = *(const float4*)&sHp[A];
        float4 w1 = *(const float4*)&sHp[A + 4];
        float4 w2 = *(const float4*)&sHp[A + 8];
        W[0]=w0.x; W[1]=w0.y; W[2]=w0.z; W[3]=w0.w;
        W[4]=w1.x; W[5]=w1.y; W[6]=w1.z; W[7]=w1.w;
        W[8]=w2.x; W[9]=w2.y; W[10]=w2.z; W[11]=w2.w;
    }
    #pragma unroll
    for (int s4 = 0; s4 < 22; ++s4) {
        const int q = s4 * 4;
        float4 tp = *(const float4*)&staps[q];     // broadcast
        float tv[4] = { tp.x, tp.y, tp.z, tp.w };
        #pragma unroll
        for (int j = 0; j < 4; ++j)
            #pragma unroll
            for (int k = 0; k < 8; ++k)
                acc[k] += tv[j] * W[j + k];
        if (s4 < 21) {
            #pragma unroll
            for (int m = 0; m < 8; ++m) W[m] = W[m + 4];
            float4 nw = *(const float4*)&sHp[A + q + 12];
            W[8]=nw.x; W[9]=nw.y; W[10]=nw.z; W[11]=nw.w;
        }
    }

    // write H_est fp32 + hi/lo bf16 planes
    float*  hout = out + XTOT + (size_t)n * Pp;
    {
        float4 o0 = { acc[0], acc[1], acc[2], acc[3] };
        float4 o1 = { acc[4], acc[5], acc[6], acc[7] };
        *(float4*)&hout[i0]     = o0;
        *(float4*)&hout[i0 + 4] = o1;
    }
    ushort8 vh, vl;
    #pragma unroll
    for (int k = 0; k < 8; ++k) {
        uint32_t rh = bf16rn(acc[k]);
        float hf = __uint_as_float(rh << 16);
        uint32_t rl = bf16rn(acc[k] - hf);
        vh[k] = (ushort)rh;
        vl[k] = (ushort)rl;
    }
    *(ushort8*)&whi[(size_t)n * Pp + i0] = vh;
    *(ushort8*)&wlo[(size_t)n * Pp + i0] = vl;
}

// ===================== Kernel 2: banded Toeplitz GEMM (bf16 MFMA, 3-pass) ====
constexpr int BN2 = 128;
constexpr int BT2 = 128;
constexpr int BK2 = 32;
constexpr int NB2 = Nn / BN2;          // 64
constexpr int TB2 = 3072 / BT2;        // 24
constexpr int NWG = NB2 * TB2;         // 1536 (% 8 == 0, bijective XCD swizzle)
constexpr int RSTR = 1280;             // replica stride; covers alg+7 <= 1271 (OOB fix)

__global__ __launch_bounds__(TPB, 2)
void toep_gemm(const float* __restrict__ v,
               const ushort* __restrict__ whi,
               const ushort* __restrict__ wlo,
               float* __restrict__ out)
{
    __shared__ alignas(16) ushort sA[2][2][BN2 * BK2];   // 32 KB
    __shared__ alignas(16) ushort sRV[2][8 * RSTR];      // 40 KB

    const int tid  = threadIdx.x;
    const int lane = tid & 63;
    const int w    = tid >> 6;

    int bid = blockIdx.x;
    int wg  = (bid & 7) * (NWG / 8) + (bid >> 3);
    const int nb = wg / TB2;
    const int tb = wg - nb * TB2;
    const int n0 = nb * BN2;
    const int t0 = tb * BT2;

    // replicated reversed v: replica r at position m holds q = m + r - 128,
    // RV(q) = v[1023-q] for q in [0,1024), else 0.  (hi and lo bf16 planes)
    // Any read with q outside [0,1024) lands on a stored 0 within bounds.
    for (int idx = tid; idx < 8 * RSTR; idx += TPB) {
        int r = idx / RSTR, m = idx - r * RSTR;
        int q = m + r - 128;
        float val = (q >= 0 && q < Ll) ? v[1023 - q] : 0.0f;
        uint32_t rh = bf16rn(val);
        float hf = __uint_as_float(rh << 16);
        uint32_t rl = bf16rn(val - hf);
        sRV[0][idx] = (ushort)rh;
        sRV[1][idx] = (ushort)rl;
    }

    const int u       = t0 >> 5;
    const int s_begin = max(0, 32 - u);
    const int s_end   = min(36, 96 - u);
    const int jstart  = t0 - 1024;

    auto stage = [&](int buf, int s) {
        int j0 = jstart + (s << 5);
        #pragma unroll
        for (int hl = 0; hl < 2; ++hl) {
            const ushort* src = hl ? wlo : whi;
            #pragma unroll
            for (int i = 0; i < 2; ++i) {
                int slotb = w * 128 + i * 64;        // wave-uniform
                int slot  = slotb + lane;
                int row   = slot >> 2, pc = slot & 3;
                int gs    = pc ^ ((row >> 1) & 3);   // pre-swizzled source chunk
                const ushort* g = src + (size_t)(n0 + row) * Pp + (j0 + gs * 8);
                gload16(g, (void*)&sA[buf][hl][slotb * 8]);
            }
        }
    };

    f32x4 acc[2][8];
    #pragma unroll
    for (int a = 0; a < 2; ++a)
        #pragma unroll
        for (int b = 0; b < 8; ++b)
            acc[a][b] = (f32x4){0.f, 0.f, 0.f, 0.f};

    int cur = 0;
    stage(0, s_begin);
    __syncthreads();

    for (int s = s_begin; s < s_end; ++s) {
        if (s + 1 < s_end) stage(cur ^ 1, s + 1);

        // A fragments (row = w*32 + fr*16 + (l&15), k-chunk g = l>>4, XOR-swizzled)
        short8 ah[2], alo[2];
        #pragma unroll
        for (int fr = 0; fr < 2; ++fr) {
            int row = (w << 5) + (fr << 4) + (lane & 15);
            int g   = lane >> 4;
            int pc  = g ^ ((row >> 1) & 3);
            int off = row * 32 + pc * 8;
            ah[fr]  = *(const short8*)&sA[cur][0][off];
            alo[fr] = *(const short8*)&sA[cur][1][off];
        }

        // B fragments straight from replicated reversed v
        int sBase = (s << 5) + 127 + ((lane >> 4) << 3) - (lane & 15);
        #pragma unroll
        for (int cc = 0; cc < 8; ++cc) {
            int b   = sBase - (cc << 4);
            int rep = b & 7, alg = b & ~7;
            int off = rep * RSTR + alg;
            short8 bh = *(const short8*)&sRV[0][off];
            short8 bl = *(const short8*)&sRV[1][off];
            #pragma unroll
            for (int fr = 0; fr < 2; ++fr) {
                acc[fr][cc] = __builtin_amdgcn_mfma_f32_16x16x32_bf16(ah[fr],  bh, acc[fr][cc], 0, 0, 0);
                acc[fr][cc] = __builtin_amdgcn_mfma_f32_16x16x32_bf16(ah[fr],  bl, acc[fr][cc], 0, 0, 0);
                acc[fr][cc] = __builtin_amdgcn_mfma_f32_16x16x32_bf16(alo[fr], bh, acc[fr][cc], 0, 0, 0);
            }
        }
        __syncthreads();
        cur ^= 1;
    }

    // C/D: col = l&15, row = 4*(l>>4) + i
    #pragma unroll
    for (int fr = 0; fr < 2; ++fr) {
        #pragma unroll
        for (int cc = 0; cc < 8; ++cc) {
            int t = t0 + (cc << 4) + (lane & 15);
            if (t < XLEN) {
                int nbase = n0 + (w << 5) + (fr << 4) + ((lane >> 4) << 2);
                #pragma unroll
                for (int i = 0; i < 4; ++i) {
                    int nn = nbase + i;
                    int mi = nn >> 9, ki = nn & 511;
                    out[(size_t)(ki * Mm + mi) * XLEN + t] = acc[fr][cc][i];
                }
            }
        }
    }
}

// ===================== Legacy fallback (R1 monolith) =========================
__global__ __launch_bounds__(TPB, 4)
void fused_row_kernel(const float* __restrict__ U,
                      const float* __restrict__ Hn,
                      const float* __restrict__ v,
                      const float* __restrict__ mtoa,
                      float* __restrict__ out)
{
    __shared__ float swin[Dd];
    __shared__ float stap[81];
    __shared__ float sHp[HPLEN];
    __shared__ float shc[HCLEN];
    __shared__ float svs[Ll];
    __shared__ float sval[TPB];
    __shared__ int   sidx[TPB];

    const int n   = blockIdx.x;
    const int tid = threadIdx.x;
    const int m_i = n >> 9;
    const int k_i = n & 511;

    *(float4*)&svs[tid * 4] = ((const float4*)v)[tid];
    {
        const float4* h4 = (const float4*)(Hn + (size_t)n * Pp);
        *(float4*)&sHp[HPAD + tid * 8]     = h4[tid * 2];
        *(float4*)&sHp[HPAD + tid * 8 + 4] = h4[tid * 2 + 1];
    }
    for (int j = tid; j < HPAD; j += TPB) sHp[j] = 0.0f;
    for (int j = tid; j < HPLEN - (HPAD + Pp); j += TPB) sHp[HPAD + Pp + j] = 0.0f;
    for (int j = tid; j < 1024; j += TPB) {
        shc[j] = 0.0f;
        shc[1024 + Pp + j] = 0.0f;
    }

    const float u  = U[n];
    const float mt = mtoa[n];
    float th = tanhf(u);
    if (isnan(th)) th = 0.0f;
    const float delta = 0.02f * th;
    const float frac  = delta * 16000.0f;
    const float af    = fabsf(frac);
    float nt = delta + mt;
    if (nt == 0.0f) nt = 1.0f;
    const float ratio = mt / nt;
    const bool  isneg = frac < 0.0f;

    for (int t = tid; t < Dd; t += TPB) {
        float T  = (float)(t - SO) - af;
        float c  = cosf((6.28318530717958648f * T) / 80.0f);
        float px = 3.14159265358979324f * T;
        float sc = (T == 0.0f) ? 1.0f : (sinf(px) / px);
        float w  = ratio * 0.5f;
        w = w * (1.0f + c);
        w = w * sc;
        swin[t] = w;
    }
    __syncthreads();

    float lv = swin[tid];
    int   li = tid;
    {
        int t2 = tid + TPB;
        if (t2 < Dd) {
            float v2 = swin[t2];
            if (v2 > lv) { lv = v2; li = t2; }
        }
    }
    sval[tid] = lv; sidx[tid] = li;
    __syncthreads();
    for (int s = TPB / 2; s > 0; s >>= 1) {
        if (tid < s) {
            float av = sval[tid];     int ai = sidx[tid];
            float bv = sval[tid + s]; int bi = sidx[tid + s];
            if (bv > av || (bv == av && bi < ai)) { sval[tid] = bv; sidx[tid] = bi; }
        }
        __syncthreads();
    }
    const int am = sidx[0];

    if (tid < 81) {
        int w = am - 40 + tid;
        stap[tid] = (w >= 0 && w < Dd) ? swin[w] : 0.0f;
    }
    __syncthreads();

    const int sgn = isneg ? -1 : 1;
    float* hout = out + XTOT + (size_t)n * Pp;
    for (int j = 0; j < Pp / TPB; ++j) {
        int i = tid + j * TPB;
        int base = HPAD + i + sgn * (80 - am);
        float acc = 0.0f;
        #pragma unroll
        for (int p = 0; p < 81; ++p)
            acc += stap[p] * sHp[base - sgn * p];
        hout[i] = acc;
        shc[1024 + i] = acc;
    }
    __syncthreads();

    const int t0 = tid * 12;
    float acc[12];
    #pragma unroll
    for (int i = 0; i < 12; ++i) acc[i] = 0.0f;

    int kend = t0 + 11;            if (kend > Ll - 1) kend = Ll - 1;
    int kstart = t0 - (Pp - 1);    if (kstart < 0)     kstart = 0;
    kstart &= ~3;

    for (int k0 = kstart; k0 <= kend; k0 += 4) {
        float4 vv = *(const float4*)&svs[k0];
        int A = 1024 + t0 - k0 - 4;
        float4 w0 = *(const float4*)&shc[A];
        float4 w1 = *(const float4*)&shc[A + 4];
        float4 w2 = *(const float4*)&shc[A + 8];
        float4 w3 = *(const float4*)&shc[A + 12];
        float W[16] = { w0.x, w0.y, w0.z, w0.w,
                        w1.x, w1.y, w1.z, w1.w,
                        w2.x, w2.y, w2.z, w2.w,
                        w3.x, w3.y, w3.z, w3.w };
        float vk[4] = { vv.x, vv.y, vv.z, vv.w };
        #pragma unroll
        for (int kk = 0; kk < 4; ++kk) {
            #pragma unroll
            for (int i = 0; i < 12; ++i)
                acc[i] += vk[kk] * W[i - kk + 4];
        }
    }

    float* xrow = out + (size_t)(k_i * Mm + m_i) * XLEN;
    #pragma unroll
    for (int i = 0; i < 12; ++i) {
        int t = t0 + i;
        if (t < XLEN) xrow[t] = acc[i];
    }
}

extern "C" void kernel_launch(void* const* d_in, const int* in_sizes, int n_in,
                              void* d_out, int out_size, void* d_ws, size_t ws_size,
                              hipStream_t stream) {
    const float* U    = (const float*)d_in[0];
    const float* Hn   = (const float*)d_in[1];
    const float* v    = (const float*)d_in[2];
    const float* mtoa = (const float*)d_in[3];
    float* out = (float*)d_out;

    const size_t need = (size_t)Nn * Pp * sizeof(ushort) * 2;  // hi+lo = 67.1 MB
    if (ws_size >= need) {
        ushort* whi = (ushort*)d_ws;
        ushort* wlo = whi + (size_t)Nn * Pp;
        winconv_kernel<<<Nn, TPB, 0, stream>>>(U, Hn, mtoa, out, whi, wlo);
        toep_gemm<<<NWG, TPB, 0, stream>>>(v, whi, wlo, out);
    } else {
        fused_row_kernel<<<Nn, TPB, 0, stream>>>(U, Hn, v, mtoa, out);
    }
}